// Round 1
// baseline (51.012 us; speedup 1.0000x reference)
//
#include <hip/hip_runtime.h>
#include <hip/hip_bf16.h>
#include <float.h>

typedef __attribute__((ext_vector_type(8))) _Float16 f16x8;
typedef __attribute__((ext_vector_type(4))) _Float16 f16x4;
typedef __attribute__((ext_vector_type(4))) float f32x4;

#define WIN 128
#define KEYS 256
#define DH 64
#define NWIN 32
#define SEQ 4096
#define QS 72     // q LDS row stride (elems)
#define KSTR 72   // k LDS row stride
#define VSTR 264  // v^T LDS row stride (keys + 8 pad)
#define PSTR 136  // p LDS row stride (128 keys + 8 pad)
// log2(10000)/32
#define L2B_OVER 0.41524101186092156f

__launch_bounds__(512, 1)
__global__ void lattn_kernel(const float* __restrict__ q,
                             const float* __restrict__ k,
                             const float* __restrict__ v,
                             float* __restrict__ out) {
  __shared__ __align__(16) _Float16 qsm[WIN * QS];      // 18 KB, rope'd+scaled
  __shared__ __align__(16) _Float16 ksm[KEYS * KSTR];   // 36 KB, rope'd
  __shared__ __align__(16) _Float16 vsm[DH * VSTR];     // 33 KB, transposed [d][key]
  __shared__ __align__(16) _Float16 psm[8 * 16 * PSTR]; // 34 KB, per-wave P half-tiles

  const int bid  = blockIdx.x;
  const int bh   = bid >> 5;
  const int win  = bid & 31;
  const int tid  = threadIdx.x;
  const int wv   = tid >> 6;
  const int lane = tid & 63;
  const int c    = lane & 15;
  const int g    = lane >> 4;

  const float* qb = q + ((size_t)bh * SEQ + (size_t)win * WIN) * DH;

  // ---- stage Q: 128 rows x 8 dim-quads (pair d with d+32, same freq) ----
  #pragma unroll
  for (int it = 0; it < 2; ++it) {
    int item = it * 512 + tid;
    int row = item >> 3, p = item & 7;
    const float4* src = (const float4*)(qb + row * DH);
    float4 lo = src[p];
    float4 hi = src[p + 8];
    float pos = (float)(128 + row);
    f16x4 rl, rh;
    #pragma unroll
    for (int j = 0; j < 4; ++j) {
      float invf = exp2f(-(float)(4 * p + j) * L2B_OVER);
      float sn, cs;
      __sincosf(pos * invf, &sn, &cs);
      float x = ((const float*)&lo)[j];
      float y = ((const float*)&hi)[j];
      rl[j] = (_Float16)((x * cs - y * sn) * 0.125f);
      rh[j] = (_Float16)((y * cs + x * sn) * 0.125f);
    }
    *(f16x4*)(&qsm[row * QS + 4 * p])      = rl;
    *(f16x4*)(&qsm[row * QS + 4 * p + 32]) = rh;
  }

  // ---- stage K: 256 rows (window-1 .. window), rope'd, pad rows = 0 (masked) ----
  #pragma unroll
  for (int it = 0; it < 4; ++it) {
    int item = it * 512 + tid;
    int row = item >> 3, p = item & 7;
    long grow = (long)win * WIN - WIN + row;
    float4 lo = {0.f, 0.f, 0.f, 0.f}, hi = {0.f, 0.f, 0.f, 0.f};
    if (grow >= 0) {
      const float4* src = (const float4*)(k + ((size_t)bh * SEQ + grow) * DH);
      lo = src[p];
      hi = src[p + 8];
    }
    float pos = (float)row;
    f16x4 rl, rh;
    #pragma unroll
    for (int j = 0; j < 4; ++j) {
      float invf = exp2f(-(float)(4 * p + j) * L2B_OVER);
      float sn, cs;
      __sincosf(pos * invf, &sn, &cs);
      float x = ((const float*)&lo)[j];
      float y = ((const float*)&hi)[j];
      rl[j] = (_Float16)(x * cs - y * sn);
      rh[j] = (_Float16)(y * cs + x * sn);
    }
    *(f16x4*)(&ksm[row * KSTR + 4 * p])      = rl;
    *(f16x4*)(&ksm[row * KSTR + 4 * p + 32]) = rh;
  }

  // ---- stage V transposed: vsm[d][key] ----
  #pragma unroll
  for (int it = 0; it < 8; ++it) {
    int item = it * 512 + tid;
    int row = item >> 4, p = item & 15;
    long grow = (long)win * WIN - WIN + row;
    float4 val = {0.f, 0.f, 0.f, 0.f};
    if (grow >= 0)
      val = *(const float4*)(v + ((size_t)bh * SEQ + grow) * DH + 4 * p);
    #pragma unroll
    for (int i = 0; i < 4; ++i)
      vsm[(4 * p + i) * VSTR + row] = (_Float16)(((const float*)&val)[i]);
  }

  __syncthreads();

  // ---- QK^T (swapped: A=K rows=keys, B=Q cols=queries) -> S^T per wave ----
  // Wave wv owns queries [16*wv, 16*wv+16). C layout: key = 16*mt + 4*g + r, query col = c.
  f16x8 qf[2];
  #pragma unroll
  for (int ks = 0; ks < 2; ++ks)
    qf[ks] = *(const f16x8*)(&qsm[(16 * wv + c) * QS + 32 * ks + 8 * g]);

  f32x4 acc[16];
  #pragma unroll
  for (int mt = 0; mt < 16; ++mt) acc[mt] = (f32x4){0.f, 0.f, 0.f, 0.f};

  #pragma unroll
  for (int mt = 0; mt < 16; ++mt) {
    #pragma unroll
    for (int ks = 0; ks < 2; ++ks) {
      f16x8 kf = *(const f16x8*)(&ksm[(16 * mt + c) * KSTR + 32 * ks + 8 * g]);
      acc[mt] = __builtin_amdgcn_mfma_f32_16x16x32_f16(kf, qf[ks], acc[mt], 0, 0, 0);
    }
  }

  // ---- masked softmax over keys (in-register; 64 vals/lane + 2 shuffles) ----
  const int qi   = 16 * wv + c;            // query index within window
  const int kmin = (win == 0) ? 128 : 0;   // pad mask for first window
  float m = -FLT_MAX;
  #pragma unroll
  for (int mt = 0; mt < 16; ++mt) {
    #pragma unroll
    for (int r = 0; r < 4; ++r) {
      int j = 16 * mt + 4 * g + r;
      bool ok = (j <= qi + 128) && (j >= kmin);
      float s = ok ? acc[mt][r] : -FLT_MAX;
      acc[mt][r] = s;
      m = fmaxf(m, s);
    }
  }
  m = fmaxf(m, __shfl_xor(m, 16));
  m = fmaxf(m, __shfl_xor(m, 32));

  float sm = 0.f;
  #pragma unroll
  for (int mt = 0; mt < 16; ++mt) {
    #pragma unroll
    for (int r = 0; r < 4; ++r) {
      float p = __expf(acc[mt][r] - m);   // masked -> exp(-huge) = 0
      acc[mt][r] = p;
      sm += p;
    }
  }
  sm += __shfl_xor(sm, 16);
  sm += __shfl_xor(sm, 32);
  const float rinv = 1.0f / sm;

  // ---- PV: stage P (fp16) to per-wave LDS in two key-halves, MFMA A=P, B=V^T ----
  f32x4 oacc[4];
  #pragma unroll
  for (int nt = 0; nt < 4; ++nt) oacc[nt] = (f32x4){0.f, 0.f, 0.f, 0.f};

  _Float16* pw = &psm[wv * 16 * PSTR];

  #pragma unroll
  for (int h = 0; h < 2; ++h) {
    if (h) {  // WAR: previous half's reads must complete before overwrite
      asm volatile("s_waitcnt lgkmcnt(0)" ::: "memory");
      __builtin_amdgcn_sched_barrier(0);
    }
    #pragma unroll
    for (int mt8 = 0; mt8 < 8; ++mt8) {
      int mt = 8 * h + mt8;
      f16x4 pv4;
      #pragma unroll
      for (int r = 0; r < 4; ++r) pv4[r] = (_Float16)(acc[mt][r] * rinv);
      *(f16x4*)(&pw[c * PSTR + 16 * mt8 + 4 * g]) = pv4;
    }
    asm volatile("s_waitcnt lgkmcnt(0)" ::: "memory");
    __builtin_amdgcn_sched_barrier(0);

    #pragma unroll
    for (int ks = 0; ks < 4; ++ks) {
      f16x8 pf = *(const f16x8*)(&pw[c * PSTR + 32 * ks + 8 * g]);
      #pragma unroll
      for (int nt = 0; nt < 4; ++nt) {
        f16x8 vf = *(const f16x8*)(&vsm[(16 * nt + c) * VSTR + 128 * h + 32 * ks + 8 * g]);
        oacc[nt] = __builtin_amdgcn_mfma_f32_16x16x32_f16(pf, vf, oacc[nt], 0, 0, 0);
      }
    }
  }

  // ---- write O: row = 16*wv + 4*g + r, col = 16*nt + c ----
  float* ob = out + ((size_t)bh * SEQ + (size_t)win * WIN + 16 * wv) * DH;
  #pragma unroll
  for (int nt = 0; nt < 4; ++nt) {
    #pragma unroll
    for (int r = 0; r < 4; ++r) {
      ob[(4 * g + r) * DH + 16 * nt + c] = oacc[nt][r];
    }
  }
}

extern "C" void kernel_launch(void* const* d_in, const int* in_sizes, int n_in,
                              void* d_out, int out_size, void* d_ws, size_t ws_size,
                              hipStream_t stream) {
  const float* q = (const float*)d_in[0];
  const float* k = (const float*)d_in[1];
  const float* v = (const float*)d_in[2];
  float* out = (float*)d_out;
  dim3 grid(32 * 32);  // (bh=32) x (windows=32)
  lattn_kernel<<<grid, 512, 0, stream>>>(q, k, v, out);
}

// Round 3
// 43.341 us; speedup vs baseline: 1.1770x; 1.1770x over previous
//
#include <hip/hip_runtime.h>
#include <float.h>

typedef __attribute__((ext_vector_type(8))) _Float16 f16x8;
typedef __attribute__((ext_vector_type(4))) _Float16 f16x4;
typedef __attribute__((ext_vector_type(4))) float f32x4;

#define WIN 128
#define SEQ 4096
#define DH 64
#define KSTR 72     // K LDS row stride (elems)
#define VSTR 264    // V^T LDS row stride (256 keys + 8 pad)
#define PSTR 136    // P LDS row stride (128 keys + 8 pad)
#define VOFF 36864  // byte offset of V region
// log2(10000)/32
#define L2B_OVER 0.41524101186092156f

// LDS: 36,864 (K, later aliased by P = 34,816) + 33,792 (V^T) = 70,656 -> 2 blocks/CU
__launch_bounds__(512, 4)
__global__ void lattn_kernel(const float* __restrict__ q,
                             const float* __restrict__ k,
                             const float* __restrict__ v,
                             float* __restrict__ out) {
  __shared__ __align__(16) char smem[70656];
  _Float16* ksm = (_Float16*)smem;           // [256 keys][72]
  _Float16* psm = (_Float16*)smem;           // aliased after 2nd barrier: 8 waves x [16 q][136]
  _Float16* vsm = (_Float16*)(smem + VOFF);  // [64 d][264 keys] transposed

  const int bid  = blockIdx.x;
  const int lbid = (bid & 7) * 128 + (bid >> 3);  // bijective XCD swizzle (1024 = 8*128)
  const int bh   = lbid >> 5;
  const int win  = lbid & 31;
  const int tid  = threadIdx.x;
  const int wv   = tid >> 6;
  const int lane = tid & 63;
  const int c    = lane & 15;
  const int g    = lane >> 4;

  // ---- per-wave Q load: global -> regs ----
  const int qrow = 16 * wv + c;
  const float* qp = q + ((size_t)bh * SEQ + (size_t)win * WIN + qrow) * DH;
  const float4 x0 = *(const float4*)(qp + 8 * g);
  const float4 x1 = *(const float4*)(qp + 8 * g + 4);
  const float4 y0 = *(const float4*)(qp + 8 * g + 32);
  const float4 y1 = *(const float4*)(qp + 8 * g + 36);

  // ---- stage K: rope'd fp16; wave-remapped so stores spread banks ----
  // row = c + 16*(hi>>1), p = g + 4*(hi&1), hi = it*8 + wv
  #pragma unroll
  for (int it = 0; it < 4; ++it) {
    int hi  = it * 8 + wv;
    int row = c + 16 * (hi >> 1);
    int p   = g + 4 * (hi & 1);
    long grow = (long)win * WIN - WIN + row;
    float4 lo = {0.f, 0.f, 0.f, 0.f}, hi4 = {0.f, 0.f, 0.f, 0.f};
    if (grow >= 0) {
      const float4* src = (const float4*)(k + ((size_t)bh * SEQ + grow) * DH);
      lo  = src[p];
      hi4 = src[p + 8];
    }
    float pos = (float)row;
    f16x4 rl, rh;
    #pragma unroll
    for (int j = 0; j < 4; ++j) {
      float sn, cs;
      __sincosf(pos * exp2f(-(float)(4 * p + j) * L2B_OVER), &sn, &cs);
      float x = ((const float*)&lo)[j];
      float y = ((const float*)&hi4)[j];
      rl[j] = (_Float16)(x * cs - y * sn);
      rh[j] = (_Float16)(y * cs + x * sn);
    }
    *(f16x4*)(&ksm[row * KSTR + 4 * p])      = rl;
    *(f16x4*)(&ksm[row * KSTR + 4 * p + 32]) = rh;
  }

  // ---- stage V^T: wave covers 16 keys x 4 d-quads -> transposed stores ~2-way ----
  // row(key) = c + 16*(hi&15), pf = g + 4*(hi>>4), hi = it*8 + wv in [0,64)
  #pragma unroll
  for (int it = 0; it < 8; ++it) {
    int hi  = it * 8 + wv;
    int row = c + 16 * (hi & 15);
    int pf  = g + 4 * (hi >> 4);
    long grow = (long)win * WIN - WIN + row;
    float4 val = {0.f, 0.f, 0.f, 0.f};
    if (grow >= 0)
      val = *(const float4*)(v + ((size_t)bh * SEQ + grow) * DH + 4 * pf);
    #pragma unroll
    for (int i = 0; i < 4; ++i)
      vsm[(4 * pf + i) * VSTR + row] = (_Float16)(((const float*)&val)[i]);
  }

  // ---- rope Q into B-fragments ----
  f16x8 qf0, qf1;
  {
    float pos = (float)(128 + qrow);
    #pragma unroll
    for (int j = 0; j < 4; ++j) {
      float sn, cs;
      __sincosf(pos * exp2f(-(float)(8 * g + j) * L2B_OVER), &sn, &cs);
      float xa = ((const float*)&x0)[j], ya = ((const float*)&y0)[j];
      qf0[j]     = (_Float16)((xa * cs - ya * sn) * 0.125f);
      qf1[j]     = (_Float16)((ya * cs + xa * sn) * 0.125f);
      __sincosf(pos * exp2f(-(float)(8 * g + 4 + j) * L2B_OVER), &sn, &cs);
      float xb = ((const float*)&x1)[j], yb = ((const float*)&y1)[j];
      qf0[4 + j] = (_Float16)((xb * cs - yb * sn) * 0.125f);
      qf1[4 + j] = (_Float16)((yb * cs + xb * sn) * 0.125f);
    }
  }

  __syncthreads();

  // ---- QK^T (swapped: A=K -> S^T). key = 16*mt + 4*g + r, query = c ----
  f32x4 acc[16];
  #pragma unroll
  for (int mt = 0; mt < 16; ++mt) acc[mt] = (f32x4){0.f, 0.f, 0.f, 0.f};

  #pragma unroll
  for (int mt = 0; mt < 16; ++mt) {
    f16x8 kf0 = *(const f16x8*)(&ksm[(16 * mt + c) * KSTR + 8 * g]);
    f16x8 kf1 = *(const f16x8*)(&ksm[(16 * mt + c) * KSTR + 32 + 8 * g]);
    acc[mt] = __builtin_amdgcn_mfma_f32_16x16x32_f16(kf0, qf0, acc[mt], 0, 0, 0);
    acc[mt] = __builtin_amdgcn_mfma_f32_16x16x32_f16(kf1, qf1, acc[mt], 0, 0, 0);
  }

  // ---- masked softmax over keys ----
  const int qi   = qrow;
  const int kmin = (win == 0) ? 128 : 0;
  float m = -FLT_MAX;
  #pragma unroll
  for (int mt = 0; mt < 16; ++mt) {
    #pragma unroll
    for (int r = 0; r < 4; ++r) {
      int j = 16 * mt + 4 * g + r;
      bool ok = (j <= qi + 128) && (j >= kmin);
      float s = ok ? acc[mt][r] : -FLT_MAX;
      acc[mt][r] = s;
      m = fmaxf(m, s);
    }
  }
  m = fmaxf(m, __shfl_xor(m, 16));
  m = fmaxf(m, __shfl_xor(m, 32));

  float sm = 0.f;
  #pragma unroll
  for (int mt = 0; mt < 16; ++mt) {
    #pragma unroll
    for (int r = 0; r < 4; ++r) {
      float p = __expf(acc[mt][r] - m);
      acc[mt][r] = p;
      sm += p;
    }
  }
  sm += __shfl_xor(sm, 16);
  sm += __shfl_xor(sm, 32);
  const float rinv = 1.0f / sm;

  __syncthreads();  // all ksm reads done -> safe to alias with psm

  // ---- PV: P via per-wave LDS tile, V^T via b128 reads (proven R1 path) ----
  f32x4 oacc[4];
  #pragma unroll
  for (int nt = 0; nt < 4; ++nt) oacc[nt] = (f32x4){0.f, 0.f, 0.f, 0.f};

  _Float16* pw = psm + wv * 16 * PSTR;

  #pragma unroll
  for (int h = 0; h < 2; ++h) {
    if (h) {  // WAR: previous half's P reads must complete before overwrite
      asm volatile("s_waitcnt lgkmcnt(0)" ::: "memory");
      __builtin_amdgcn_sched_barrier(0);
    }
    #pragma unroll
    for (int mt8 = 0; mt8 < 8; ++mt8) {
      int mt = 8 * h + mt8;
      f16x4 pv4;
      #pragma unroll
      for (int r = 0; r < 4; ++r) pv4[r] = (_Float16)(acc[mt][r] * rinv);
      *(f16x4*)(&pw[c * PSTR + 16 * mt8 + 4 * g]) = pv4;
    }
    asm volatile("s_waitcnt lgkmcnt(0)" ::: "memory");
    __builtin_amdgcn_sched_barrier(0);

    #pragma unroll
    for (int ks = 0; ks < 4; ++ks) {
      f16x8 pf = *(const f16x8*)(&pw[c * PSTR + 32 * ks + 8 * g]);
      #pragma unroll
      for (int nt = 0; nt < 4; ++nt) {
        f16x8 vf = *(const f16x8*)(&vsm[(16 * nt + c) * VSTR + 128 * h + 32 * ks + 8 * g]);
        oacc[nt] = __builtin_amdgcn_mfma_f32_16x16x32_f16(pf, vf, oacc[nt], 0, 0, 0);
      }
    }
  }

  // ---- write O: row = 16*wv + 4*g + r, col = 16*nt + c ----
  float* ob = out + ((size_t)bh * SEQ + (size_t)win * WIN + 16 * wv) * DH;
  #pragma unroll
  for (int nt = 0; nt < 4; ++nt) {
    #pragma unroll
    for (int r = 0; r < 4; ++r) {
      ob[(4 * g + r) * DH + 16 * nt + c] = oacc[nt][r];
    }
  }
}

extern "C" void kernel_launch(void* const* d_in, const int* in_sizes, int n_in,
                              void* d_out, int out_size, void* d_ws, size_t ws_size,
                              hipStream_t stream) {
  const float* q = (const float*)d_in[0];
  const float* k = (const float*)d_in[1];
  const float* v = (const float*)d_in[2];
  float* out = (float*)d_out;
  dim3 grid(32 * 32);
  lattn_kernel<<<grid, 512, 0, stream>>>(q, k, v, out);
}